// Round 1
// baseline (540.868 us; speedup 1.0000x reference)
//
#include <hip/hip_runtime.h>
#include <hip/hip_bf16.h>

#define BB 2
#define NN 2048
#define DIMM 512
#define HH 8
#define DHH 64
#define EPSF 1e-5f

// ---------------------------------------------------------------------------
// Tiled fp32 GEMM: out = A[4096,512] @ W[512,512] + bias
// split_heads=1: out laid out [B,H,N,DH]; else flat [4096,512].
// BM=64, BN=64 (== one head), BK=32. 256 threads, 4x4 register tile.
// ---------------------------------------------------------------------------
__global__ __launch_bounds__(256) void gemm_kernel(
    const float* __restrict__ A, const float* __restrict__ W,
    const float* __restrict__ bias, float* __restrict__ out, int split_heads) {
  __shared__ float As[32][68];  // k-major: As[kk][row]
  __shared__ float Bs[32][68];  // Bs[kk][col]

  const int t = threadIdx.x;
  const int r0 = blockIdx.x * 64;
  const int c0 = blockIdx.y * 64;
  const int tr = ((t >> 4) & 15) << 2;  // 0..60
  const int tc = (t & 15) << 2;         // 0..60

  float acc[4][4];
#pragma unroll
  for (int i = 0; i < 4; ++i)
#pragma unroll
    for (int j = 0; j < 4; ++j) acc[i][j] = 0.0f;

  for (int k0 = 0; k0 < 512; k0 += 32) {
    __syncthreads();
    // Stage A tile (64 rows x 32 k), transposed into k-major LDS.
#pragma unroll
    for (int s = t; s < 512; s += 256) {
      const int row = s >> 3, kq = s & 7;
      const float4 v =
          *(const float4*)&A[(size_t)(r0 + row) * 512 + k0 + (kq << 2)];
      As[(kq << 2) + 0][row] = v.x;
      As[(kq << 2) + 1][row] = v.y;
      As[(kq << 2) + 2][row] = v.z;
      As[(kq << 2) + 3][row] = v.w;
    }
    // Stage B tile (32 k x 64 cols), already k-major.
#pragma unroll
    for (int s = t; s < 512; s += 256) {
      const int kk = s >> 4, cq = s & 15;
      *(float4*)&Bs[kk][cq << 2] =
          *(const float4*)&W[(size_t)(k0 + kk) * 512 + c0 + (cq << 2)];
    }
    __syncthreads();
#pragma unroll
    for (int kk = 0; kk < 32; ++kk) {
      const float4 a = *(const float4*)&As[kk][tr];
      const float4 b = *(const float4*)&Bs[kk][tc];
      const float aa[4] = {a.x, a.y, a.z, a.w};
      const float bb2[4] = {b.x, b.y, b.z, b.w};
#pragma unroll
      for (int i = 0; i < 4; ++i)
#pragma unroll
        for (int j = 0; j < 4; ++j) acc[i][j] += aa[i] * bb2[j];
    }
  }

  const float4 bv = *(const float4*)&bias[c0 + tc];
  const float badd[4] = {bv.x, bv.y, bv.z, bv.w};
#pragma unroll
  for (int i = 0; i < 4; ++i) {
    const int r = r0 + tr + i;
    float4 o;
    o.x = acc[i][0] + badd[0];
    o.y = acc[i][1] + badd[1];
    o.z = acc[i][2] + badd[2];
    o.w = acc[i][3] + badd[3];
    if (split_heads) {
      const int b = r >> 11;       // r / N
      const int n = r & 2047;      // r % N
      const int h = blockIdx.y;    // col tile == head
      *(float4*)&out[(((size_t)(b * HH + h)) * NN + n) * 64 + tc] = o;
    } else {
      *(float4*)&out[(size_t)r * 512 + c0 + tc] = o;
    }
  }
}

// ---------------------------------------------------------------------------
// Per-row stats: one wave per (b,h,n) row of 64 elements.
// c1 = 0.125 + 2*dInv ; dInv = 1/(exp(-nf)+1) ; k2 = sum K^2.
// ---------------------------------------------------------------------------
__global__ __launch_bounds__(256) void stats_kernel(
    const float* __restrict__ Q, const float* __restrict__ K,
    float* __restrict__ c1a, float* __restrict__ dva, float* __restrict__ k2a) {
  const int t = threadIdx.x;
  const int lane = t & 63;
  const int row = blockIdx.x * 4 + (t >> 6);  // B*H*N = 32768 rows

  const float qv = Q[(size_t)row * 64 + lane];
  // sum over 64 lanes
  float s = qv;
#pragma unroll
  for (int off = 1; off < 64; off <<= 1) s += __shfl_xor(s, off, 64);
  const float mu = s * (1.0f / 64.0f);
  const float dvq = qv - mu;
  float v2 = dvq * dvq;
#pragma unroll
  for (int off = 1; off < 64; off <<= 1) v2 += __shfl_xor(v2, off, 64);
  const float var = v2 * (1.0f / 64.0f);
  const float sigma = sqrtf(var + EPSF);
  float as = fabsf(dvq);
#pragma unroll
  for (int off = 1; off < 64; off <<= 1) as += __shfl_xor(as, off, 64);
  const float nf = as / (sigma + EPSF);
  const float dInv = 1.0f / (__expf(-nf) + 1.0f);

  const float kv = K[(size_t)row * 64 + lane];
  float k2 = kv * kv;
#pragma unroll
  for (int off = 1; off < 64; off <<= 1) k2 += __shfl_xor(k2, off, 64);

  if (lane == 0) {
    c1a[row] = 0.125f + 2.0f * dInv;
    dva[row] = dInv;
    k2a[row] = k2;
  }
}

// ---------------------------------------------------------------------------
// Flash attention, fp32 vector ALU.
// Block = (64-query tile, head, batch). 256 threads, 4x4 register tiles.
// logits = c1[q]*qk - dInv[q]*k2[m]  (q2 term dropped: softmax-shift-invariant)
// ---------------------------------------------------------------------------
__global__ __launch_bounds__(256) void attn_kernel(
    const float* __restrict__ Q, const float* __restrict__ K,
    const float* __restrict__ V, const float* __restrict__ c1a,
    const float* __restrict__ dva, const float* __restrict__ k2a,
    float* __restrict__ attn) {
  __shared__ float Qs[64][68];  // d-major: Qs[d][q]
  __shared__ float Ks[64][68];  // d-major: Ks[d][m]
  __shared__ float Vs[64][68];  // row-major: Vs[m][d]
  __shared__ float Ps[64][68];  // Ps[m][q]
  __shared__ float c1s[64], dvs[64], k2s[64];

  const int t = threadIdx.x;
  const int qt = blockIdx.x;  // 0..31
  const int h = blockIdx.y;
  const int b = blockIdx.z;
  const size_t base = ((size_t)(b * HH + h)) * NN * 64;
  const int rowbase = (b * HH + h) * NN;
  const int q0 = qt * 64;

  // Stage Q tile (transposed) + per-query scalars.
#pragma unroll
  for (int s = t; s < 1024; s += 256) {
    const int q = s >> 4, dq = s & 15;
    const float4 v = *(const float4*)&Q[base + (size_t)(q0 + q) * 64 + (dq << 2)];
    Qs[(dq << 2) + 0][q] = v.x;
    Qs[(dq << 2) + 1][q] = v.y;
    Qs[(dq << 2) + 2][q] = v.z;
    Qs[(dq << 2) + 3][q] = v.w;
  }
  if (t < 64) {
    c1s[t] = c1a[rowbase + q0 + t];
    dvs[t] = dva[rowbase + q0 + t];
  }
  __syncthreads();

  const int q4 = t >> 4;        // 0..15
  const int k4 = t & 15;        // 0..15
  const int qr = q4 << 2;       // query sub-row 0..60
  const int kc = k4 << 2;       // key / dim sub-col 0..60

  float c1q[4], dqv[4];
#pragma unroll
  for (int i = 0; i < 4; ++i) {
    c1q[i] = c1s[qr + i];
    dqv[i] = dvs[qr + i];
  }

  float M[4], L[4], O[4][4];
#pragma unroll
  for (int i = 0; i < 4; ++i) {
    M[i] = -1e30f;
    L[i] = 0.0f;
#pragma unroll
    for (int j = 0; j < 4; ++j) O[i][j] = 0.0f;
  }

  for (int kt = 0; kt < 32; ++kt) {
    const int m0 = kt * 64;
    __syncthreads();  // protect Ks/Vs/Ps reuse
    // Stage K (transposed) and V (row-major) tiles.
#pragma unroll
    for (int s = t; s < 1024; s += 256) {
      const int m = s >> 4, dq = s & 15;
      const float4 kv =
          *(const float4*)&K[base + (size_t)(m0 + m) * 64 + (dq << 2)];
      Ks[(dq << 2) + 0][m] = kv.x;
      Ks[(dq << 2) + 1][m] = kv.y;
      Ks[(dq << 2) + 2][m] = kv.z;
      Ks[(dq << 2) + 3][m] = kv.w;
      const float4 vv =
          *(const float4*)&V[base + (size_t)(m0 + m) * 64 + (dq << 2)];
      *(float4*)&Vs[m][dq << 2] = vv;
    }
    if (t < 64) k2s[t] = k2a[rowbase + m0 + t];
    __syncthreads();

    // Scores: 4x4 per thread, full K reduction over d.
    float s4[4][4];
#pragma unroll
    for (int i = 0; i < 4; ++i)
#pragma unroll
      for (int j = 0; j < 4; ++j) s4[i][j] = 0.0f;
    for (int d = 0; d < 64; ++d) {
      const float4 qv = *(const float4*)&Qs[d][qr];
      const float4 kv = *(const float4*)&Ks[d][kc];
      const float qa[4] = {qv.x, qv.y, qv.z, qv.w};
      const float ka[4] = {kv.x, kv.y, kv.z, kv.w};
#pragma unroll
      for (int i = 0; i < 4; ++i)
#pragma unroll
        for (int j = 0; j < 4; ++j) s4[i][j] += qa[i] * ka[j];
    }

    // Logits + online softmax (16-thread groups share a query row).
    float p[4][4];
#pragma unroll
    for (int i = 0; i < 4; ++i) {
      float mx = -1e30f;
#pragma unroll
      for (int j = 0; j < 4; ++j) {
        const float lij = c1q[i] * s4[i][j] - dqv[i] * k2s[kc + j];
        p[i][j] = lij;
        mx = fmaxf(mx, lij);
      }
#pragma unroll
      for (int off = 1; off < 16; off <<= 1)
        mx = fmaxf(mx, __shfl_xor(mx, off, 64));
      const float newM = fmaxf(M[i], mx);
      const float scale = __expf(M[i] - newM);
      float sum = 0.0f;
#pragma unroll
      for (int j = 0; j < 4; ++j) {
        p[i][j] = __expf(p[i][j] - newM);
        sum += p[i][j];
      }
#pragma unroll
      for (int off = 1; off < 16; off <<= 1) sum += __shfl_xor(sum, off, 64);
      L[i] = L[i] * scale + sum;
      M[i] = newM;
#pragma unroll
      for (int j = 0; j < 4; ++j) O[i][j] *= scale;
    }

    // P -> LDS (transposed to [m][q]) for the AV product.
#pragma unroll
    for (int i = 0; i < 4; ++i)
#pragma unroll
      for (int j = 0; j < 4; ++j) Ps[kc + j][qr + i] = p[i][j];
    __syncthreads();

    // O += P @ V  (thread owns queries qr..qr+3 x dims kc..kc+3)
    for (int m = 0; m < 64; ++m) {
      const float4 pv = *(const float4*)&Ps[m][qr];
      const float4 vv = *(const float4*)&Vs[m][kc];
      const float pa[4] = {pv.x, pv.y, pv.z, pv.w};
      const float va[4] = {vv.x, vv.y, vv.z, vv.w};
#pragma unroll
      for (int i = 0; i < 4; ++i)
#pragma unroll
        for (int j = 0; j < 4; ++j) O[i][j] += pa[i] * va[j];
    }
  }

  // Epilogue: normalize, write [B,N,DIM] with heads concatenated.
#pragma unroll
  for (int i = 0; i < 4; ++i) {
    const float inv = 1.0f / L[i];
    const int n = q0 + qr + i;
    float4 o;
    o.x = O[i][0] * inv;
    o.y = O[i][1] * inv;
    o.z = O[i][2] * inv;
    o.w = O[i][3] * inv;
    *(float4*)&attn[((size_t)(b * NN + n)) * 512 + h * 64 + kc] = o;
  }
}

// ---------------------------------------------------------------------------
extern "C" void kernel_launch(void* const* d_in, const int* in_sizes, int n_in,
                              void* d_out, int out_size, void* d_ws,
                              size_t ws_size, hipStream_t stream) {
  const float* z = (const float*)d_in[0];
  const float* Wq = (const float*)d_in[1];
  const float* bq = (const float*)d_in[2];
  const float* Wk = (const float*)d_in[3];
  const float* bk = (const float*)d_in[4];
  const float* Wv = (const float*)d_in[5];
  const float* bv = (const float*)d_in[6];
  const float* Wo = (const float*)d_in[7];
  const float* bo = (const float*)d_in[8];
  float* out = (float*)d_out;

  char* ws = (char*)d_ws;
  // Q/K/V: [B,H,N,DH] = 2*8*2048*64 floats = 8 MiB each
  float* Q = (float*)(ws);
  float* K = (float*)(ws + 8388608);
  float* V = (float*)(ws + 16777216);
  float* c1 = (float*)(ws + 25165824);
  float* dv = (float*)(ws + 25296896);
  float* k2 = (float*)(ws + 25427968);
  float* attn = (float*)(ws + 25559040);  // [4096,512] = 8 MiB, end ~32.4 MiB

  const dim3 gg(64, 8), blk(256);
  hipLaunchKernelGGL(gemm_kernel, gg, blk, 0, stream, z, Wq, bq, Q, 1);
  hipLaunchKernelGGL(gemm_kernel, gg, blk, 0, stream, z, Wk, bk, K, 1);
  hipLaunchKernelGGL(gemm_kernel, gg, blk, 0, stream, z, Wv, bv, V, 1);
  hipLaunchKernelGGL(stats_kernel, dim3(8192), blk, 0, stream, Q, K, c1, dv, k2);
  hipLaunchKernelGGL(attn_kernel, dim3(32, 8, 2), blk, 0, stream, Q, K, V, c1,
                     dv, k2, attn);
  hipLaunchKernelGGL(gemm_kernel, gg, blk, 0, stream, attn, Wo, bo, out, 0);
}

// Round 2
// 306.879 us; speedup vs baseline: 1.7625x; 1.7625x over previous
//
#include <hip/hip_runtime.h>
#include <hip/hip_bf16.h>

#define HH 8
#define NNq 2048
#define EPSF 1e-5f

typedef __bf16 bf16x8 __attribute__((ext_vector_type(8)));
typedef float f32x4 __attribute__((ext_vector_type(4)));

__device__ __forceinline__ unsigned short f2bf(float f) {
  union { float f; unsigned int u; } a;
  a.f = f;
  unsigned int r = a.u + 0x7fffu + ((a.u >> 16) & 1u);
  return (unsigned short)(r >> 16);
}
__device__ __forceinline__ float bf2f(unsigned short u) {
  union { unsigned int u; float f; } a;
  a.u = ((unsigned int)u) << 16;
  return a.f;
}

// ---------------------------------------------------------------------------
// z fp32 [2M] -> bf16
// ---------------------------------------------------------------------------
__global__ __launch_bounds__(256) void convert_z(const float* __restrict__ z,
                                                 unsigned short* __restrict__ zb) {
  const int i = (blockIdx.x * 256 + threadIdx.x) * 8;
  const float4 a = *(const float4*)&z[i];
  const float4 b = *(const float4*)&z[i + 4];
  union { unsigned short us[8]; uint4 v; } o;
  o.us[0] = f2bf(a.x); o.us[1] = f2bf(a.y); o.us[2] = f2bf(a.z); o.us[3] = f2bf(a.w);
  o.us[4] = f2bf(b.x); o.us[5] = f2bf(b.y); o.us[6] = f2bf(b.z); o.us[7] = f2bf(b.w);
  *(uint4*)&zb[i] = o.v;
}

// ---------------------------------------------------------------------------
// W fp32 [512,512] (k-major rows) -> Wt bf16 [n][k] (transposed), 4 weights.
// ---------------------------------------------------------------------------
__global__ __launch_bounds__(256) void transw_kernel(
    const float* __restrict__ W0, const float* __restrict__ W1,
    const float* __restrict__ W2, const float* __restrict__ W3,
    unsigned short* __restrict__ Wt) {
  __shared__ float Tl[64][68];
  const float* W = (blockIdx.z == 0) ? W0 : (blockIdx.z == 1) ? W1
                   : (blockIdx.z == 2) ? W2 : W3;
  unsigned short* dst = Wt + (size_t)blockIdx.z * 262144;
  const int t = threadIdx.x;
  const int k0 = blockIdx.x * 64, n0 = blockIdx.y * 64;
#pragma unroll
  for (int i = 0; i < 4; ++i) {
    const int idx = t + 256 * i;
    const int row = idx >> 4, cq = (idx & 15) * 4;
    *(float4*)&Tl[row][cq] = *(const float4*)&W[(size_t)(k0 + row) * 512 + n0 + cq];
  }
  __syncthreads();
#pragma unroll
  for (int i = 0; i < 4; ++i) {
    const int idx = t + 256 * i;
    const int nr = idx >> 4, kq = (idx & 15) * 4;
    ushort4 o;
    o.x = f2bf(Tl[kq + 0][nr]);
    o.y = f2bf(Tl[kq + 1][nr]);
    o.z = f2bf(Tl[kq + 2][nr]);
    o.w = f2bf(Tl[kq + 3][nr]);
    *(ushort4*)&dst[(size_t)(n0 + nr) * 512 + k0 + kq] = o;
  }
}

// ---------------------------------------------------------------------------
// MFMA GEMM: C[4096,512] = A_bf16[4096,512] @ Wt_bf16[n][k]^T + bias.
// No LDS for operands (L2-resident); 64x64 tile, 4 waves, wave = 16-row strip.
// mode 0: fp32 flat out. mode 1: bf16 [B,H,N,64]. mode 2: bf16 Vt [B,H,64,N].
// ---------------------------------------------------------------------------
__global__ __launch_bounds__(256) void gemm_kernel(
    const unsigned short* __restrict__ A, const unsigned short* __restrict__ Wt,
    const float* __restrict__ bias, void* __restrict__ out, int mode) {
  __shared__ unsigned short T[64][72];
  const int t = threadIdx.x;
  const int w = t >> 6, lane = t & 63, ln = lane & 15, quad = lane >> 4;
  const int r0 = blockIdx.x * 64, c0 = blockIdx.y * 64;

  f32x4 acc[4];
#pragma unroll
  for (int nt = 0; nt < 4; ++nt) acc[nt] = (f32x4)(0.0f);

  const unsigned short* arow = A + (size_t)(r0 + w * 16 + ln) * 512;
#pragma unroll 4
  for (int k = 0; k < 512; k += 32) {
    const bf16x8 a = *(const bf16x8*)&arow[k + quad * 8];
#pragma unroll
    for (int nt = 0; nt < 4; ++nt) {
      const bf16x8 b =
          *(const bf16x8*)&Wt[(size_t)(c0 + nt * 16 + ln) * 512 + k + quad * 8];
      acc[nt] = __builtin_amdgcn_mfma_f32_16x16x32_bf16(a, b, acc[nt], 0, 0, 0);
    }
  }

  const int rowl = w * 16 + quad * 4;  // + r
  if (mode == 0) {
    float* of = (float*)out;
#pragma unroll
    for (int nt = 0; nt < 4; ++nt) {
      const int d = c0 + nt * 16 + ln;
      const float bv = bias[d];
#pragma unroll
      for (int r = 0; r < 4; ++r)
        of[(size_t)(r0 + rowl + r) * 512 + d] = acc[nt][r] + bv;
    }
  } else if (mode == 1) {
    unsigned short* ou = (unsigned short*)out;
    const int h = c0 >> 6;
#pragma unroll
    for (int nt = 0; nt < 4; ++nt) {
      const int d = nt * 16 + ln;
      const float bv = bias[c0 + d];
#pragma unroll
      for (int r = 0; r < 4; ++r) {
        const int rg = r0 + rowl + r;
        const int b = rg >> 11, n = rg & 2047;
        ou[((size_t)(b * HH + h) * NNq + n) * 64 + d] = f2bf(acc[nt][r] + bv);
      }
    }
  } else {
    // Vt: [B,H,64,N] via LDS transpose for coalesced writes.
    unsigned short* ou = (unsigned short*)out;
    const int h = c0 >> 6;
    const int b = r0 >> 11, n0 = r0 & 2047;
#pragma unroll
    for (int nt = 0; nt < 4; ++nt) {
      const int d = nt * 16 + ln;
      const float bv = bias[c0 + d];
#pragma unroll
      for (int r = 0; r < 4; ++r) T[d][rowl + r] = f2bf(acc[nt][r] + bv);
    }
    __syncthreads();
#pragma unroll
    for (int i = 0; i < 2; ++i) {
      const int idx = t + 256 * i;
      const int d = idx >> 3, nq = (idx & 7) * 8;
      *(uint4*)&ou[((size_t)(b * HH + h) * 64 + d) * NNq + n0 + nq] =
          *(const uint4*)&T[d][nq];
    }
  }
}

// ---------------------------------------------------------------------------
// Per-row stats from bf16 Q,K: c1 = 0.125 + 2*dInv, dInv, k2.
// ---------------------------------------------------------------------------
__global__ __launch_bounds__(256) void stats_kernel(
    const unsigned short* __restrict__ Q, const unsigned short* __restrict__ K,
    float* __restrict__ c1a, float* __restrict__ dva, float* __restrict__ k2a) {
  const int t = threadIdx.x;
  const int lane = t & 63;
  const int row = blockIdx.x * 4 + (t >> 6);

  const float qv = bf2f(Q[(size_t)row * 64 + lane]);
  float s = qv;
#pragma unroll
  for (int off = 1; off < 64; off <<= 1) s += __shfl_xor(s, off, 64);
  const float mu = s * (1.0f / 64.0f);
  const float dq = qv - mu;
  float v2 = dq * dq;
#pragma unroll
  for (int off = 1; off < 64; off <<= 1) v2 += __shfl_xor(v2, off, 64);
  const float sigma = sqrtf(v2 * (1.0f / 64.0f) + EPSF);
  float as = fabsf(dq);
#pragma unroll
  for (int off = 1; off < 64; off <<= 1) as += __shfl_xor(as, off, 64);
  const float nf = as / (sigma + EPSF);
  const float dInv = 1.0f / (__expf(-nf) + 1.0f);

  const float kv = bf2f(K[(size_t)row * 64 + lane]);
  float k2 = kv * kv;
#pragma unroll
  for (int off = 1; off < 64; off <<= 1) k2 += __shfl_xor(k2, off, 64);

  if (lane == 0) {
    c1a[row] = 0.125f + 2.0f * dInv;
    dva[row] = dInv;
    k2a[row] = k2;
  }
}

// ---------------------------------------------------------------------------
// MFMA flash attention. Block = 64 queries x (h,b); 4 waves, wave = 16 queries.
// QK^T and PV on 16x16x32 bf16 MFMA; K/V frags straight from global (L2).
// Only P round-trips LDS (wave-private strip -> no barriers at all).
// logits = c1[q]*qk - dInv[q]*k2[m]
// ---------------------------------------------------------------------------
__global__ __launch_bounds__(256) void attn_kernel(
    const unsigned short* __restrict__ Qb, const unsigned short* __restrict__ Kb,
    const unsigned short* __restrict__ Vt, const float* __restrict__ c1a,
    const float* __restrict__ dva, const float* __restrict__ k2a,
    unsigned short* __restrict__ attnb) {
  __shared__ unsigned short Ps[64][72];
  const int t = threadIdx.x;
  const int w = t >> 6, lane = t & 63, ln = lane & 15, quad = lane >> 4;
  const int qt = blockIdx.x, h = blockIdx.y, b = blockIdx.z;
  const int bh = b * HH + h;
  const size_t qkbase = (size_t)bh * NNq * 64;
  const size_t vtbase = (size_t)bh * 64 * NNq;
  const int rowbase = bh * NNq;
  const int q0 = qt * 64;

  // Q fragments (constant over the K loop).
  const int qrow = q0 + w * 16 + ln;
  const bf16x8 aq0 = *(const bf16x8*)&Qb[qkbase + (size_t)qrow * 64 + quad * 8];
  const bf16x8 aq1 = *(const bf16x8*)&Qb[qkbase + (size_t)qrow * 64 + 32 + quad * 8];

  float c1r[4], dvr[4];
#pragma unroll
  for (int r = 0; r < 4; ++r) {
    const int qr = q0 + w * 16 + quad * 4 + r;
    c1r[r] = c1a[rowbase + qr];
    dvr[r] = dva[rowbase + qr];
  }

  float M[4], L[4];
  f32x4 O[4];
#pragma unroll
  for (int r = 0; r < 4; ++r) { M[r] = -1e30f; L[r] = 0.0f; }
#pragma unroll
  for (int nt = 0; nt < 4; ++nt) O[nt] = (f32x4)(0.0f);

  for (int kt = 0; kt < 32; ++kt) {
    const int m0 = kt * 64;
    // ---- S = Q K^T ----
    f32x4 s[4];
#pragma unroll
    for (int nt = 0; nt < 4; ++nt) {
      const size_t kr = qkbase + (size_t)(m0 + nt * 16 + ln) * 64;
      const bf16x8 b0 = *(const bf16x8*)&Kb[kr + quad * 8];
      const bf16x8 b1 = *(const bf16x8*)&Kb[kr + 32 + quad * 8];
      f32x4 a = (f32x4)(0.0f);
      a = __builtin_amdgcn_mfma_f32_16x16x32_bf16(aq0, b0, a, 0, 0, 0);
      a = __builtin_amdgcn_mfma_f32_16x16x32_bf16(aq1, b1, a, 0, 0, 0);
      s[nt] = a;
    }
    float k2v[4];
#pragma unroll
    for (int nt = 0; nt < 4; ++nt) k2v[nt] = k2a[rowbase + m0 + nt * 16 + ln];

    // ---- online softmax (rows live in C-layout: row = quad*4+r) ----
    float p[4][4];  // [nt][r]
    float alr[4];
#pragma unroll
    for (int r = 0; r < 4; ++r) {
      float mx = -1e30f;
#pragma unroll
      for (int nt = 0; nt < 4; ++nt) {
        const float lg = c1r[r] * s[nt][r] - dvr[r] * k2v[nt];
        p[nt][r] = lg;
        mx = fmaxf(mx, lg);
      }
#pragma unroll
      for (int off = 1; off < 16; off <<= 1) mx = fmaxf(mx, __shfl_xor(mx, off, 64));
      const float newM = fmaxf(M[r], mx);
      const float al = __expf(M[r] - newM);
      float sum = 0.0f;
#pragma unroll
      for (int nt = 0; nt < 4; ++nt) {
        p[nt][r] = __expf(p[nt][r] - newM);
        sum += p[nt][r];
      }
#pragma unroll
      for (int off = 1; off < 16; off <<= 1) sum += __shfl_xor(sum, off, 64);
      L[r] = L[r] * al + sum;
      M[r] = newM;
      alr[r] = al;
    }
#pragma unroll
    for (int nt = 0; nt < 4; ++nt)
#pragma unroll
      for (int r = 0; r < 4; ++r) O[nt][r] *= alr[r];

    // ---- P: C-layout -> A-layout via wave-private LDS strip ----
#pragma unroll
    for (int nt = 0; nt < 4; ++nt)
#pragma unroll
      for (int r = 0; r < 4; ++r)
        Ps[w * 16 + quad * 4 + r][nt * 16 + ln] = f2bf(p[nt][r]);

    const bf16x8 pa0 = *(const bf16x8*)&Ps[w * 16 + ln][quad * 8];
    const bf16x8 pa1 = *(const bf16x8*)&Ps[w * 16 + ln][32 + quad * 8];

    // ---- O += P V ----
#pragma unroll
    for (int nt = 0; nt < 4; ++nt) {
      const size_t vr = vtbase + (size_t)(nt * 16 + ln) * NNq + m0;
      const bf16x8 vb0 = *(const bf16x8*)&Vt[vr + quad * 8];
      const bf16x8 vb1 = *(const bf16x8*)&Vt[vr + 32 + quad * 8];
      O[nt] = __builtin_amdgcn_mfma_f32_16x16x32_bf16(pa0, vb0, O[nt], 0, 0, 0);
      O[nt] = __builtin_amdgcn_mfma_f32_16x16x32_bf16(pa1, vb1, O[nt], 0, 0, 0);
    }
  }

  // ---- epilogue: normalize, write bf16 [B,N,DIM] ----
#pragma unroll
  for (int r = 0; r < 4; ++r) {
    const float inv = 1.0f / L[r];
    const int n = q0 + w * 16 + quad * 4 + r;
#pragma unroll
    for (int nt = 0; nt < 4; ++nt)
      attnb[((size_t)(b * NNq + n)) * 512 + h * 64 + nt * 16 + ln] =
          f2bf(O[nt][r] * inv);
  }
}

// ---------------------------------------------------------------------------
extern "C" void kernel_launch(void* const* d_in, const int* in_sizes, int n_in,
                              void* d_out, int out_size, void* d_ws,
                              size_t ws_size, hipStream_t stream) {
  const float* z = (const float*)d_in[0];
  const float* Wq = (const float*)d_in[1];
  const float* bq = (const float*)d_in[2];
  const float* Wk = (const float*)d_in[3];
  const float* bk = (const float*)d_in[4];
  const float* Wv = (const float*)d_in[5];
  const float* bv = (const float*)d_in[6];
  const float* Wo = (const float*)d_in[7];
  const float* bo = (const float*)d_in[8];
  float* out = (float*)d_out;

  char* ws = (char*)d_ws;
  unsigned short* zb = (unsigned short*)(ws);                  // 4 MiB
  unsigned short* Wt = (unsigned short*)(ws + 4194304);        // 2 MiB (4x512KiB)
  unsigned short* Qb = (unsigned short*)(ws + 6291456);        // 4 MiB
  unsigned short* Kb = (unsigned short*)(ws + 10485760);       // 4 MiB
  unsigned short* Vtb = (unsigned short*)(ws + 14680064);      // 4 MiB
  float* c1 = (float*)(ws + 18874368);
  float* dv = (float*)(ws + 19005440);
  float* k2 = (float*)(ws + 19136512);
  unsigned short* attnb = (unsigned short*)(ws + 19267584);    // 4 MiB

  hipLaunchKernelGGL(convert_z, dim3(1024), dim3(256), 0, stream, z, zb);
  hipLaunchKernelGGL(transw_kernel, dim3(8, 8, 4), dim3(256), 0, stream,
                     Wq, Wk, Wv, Wo, Wt);
  const dim3 gg(64, 8), blk(256);
  hipLaunchKernelGGL(gemm_kernel, gg, blk, 0, stream, zb, Wt, bq, (void*)Qb, 1);
  hipLaunchKernelGGL(gemm_kernel, gg, blk, 0, stream, zb, Wt + 262144, bk, (void*)Kb, 1);
  hipLaunchKernelGGL(gemm_kernel, gg, blk, 0, stream, zb, Wt + 524288, bv, (void*)Vtb, 2);
  hipLaunchKernelGGL(stats_kernel, dim3(8192), blk, 0, stream, Qb, Kb, c1, dv, k2);
  hipLaunchKernelGGL(attn_kernel, dim3(32, 8, 2), blk, 0, stream, Qb, Kb, Vtb,
                     c1, dv, k2, attnb);
  hipLaunchKernelGGL(gemm_kernel, gg, blk, 0, stream, attnb, Wt + 786432, bo,
                     (void*)out, 0);
}